// Round 3
// baseline (416.783 us; speedup 1.0000x reference)
//
#include <hip/hip_runtime.h>

#define NB 32
#define NM 128
#define NL 32
#define NH 512
#define NV 32000
#define NHOPS 3
#define NEG_INF -1e9f

#define VC_D 16      // v-rows per gemm_D block
#define VC_U 128     // v-rows per gemm_U block
#define NPART (NV / VC_U)   // 250 split-K partials

typedef __attribute__((ext_vector_type(8))) short bf16x8;
typedef __attribute__((ext_vector_type(4))) float f32x4;

__device__ __forceinline__ unsigned short f2bf(float x) {
    unsigned u = __float_as_uint(x);
    return (unsigned short)((u + 0x7fffu + ((u >> 16) & 1u)) >> 16);
}
__device__ __forceinline__ float bf2f(unsigned short h) {
    return __uint_as_float(((unsigned)h) << 16);
}

// ---------------------------------------------------------------------------
// gemm_D: D[b][v] = u[b] . C[v]   (M=b=32, N=v, K=h=512)
// Split-bf16: C and u each decomposed hi+lo; acc += ah*bh + ah*bl + al*bh.
// Block: 128 thr (2 waves), VC_D=16 v-rows staged to LDS as bf16 hi/lo,
// XOR-swizzled to kill the 1KB-row-stride bank conflict.
// ---------------------------------------------------------------------------
__global__ __launch_bounds__(128)
void gemm_D_kernel(const float* __restrict__ u,    // [32][512] fp32
                   const float* __restrict__ Ct,   // [NV][512] table
                   float* __restrict__ D) {        // [32][NV]
    __shared__ __align__(16) unsigned short Ch[VC_D * NH];
    __shared__ __align__(16) unsigned short Cl[VC_D * NH];
    const int tid = threadIdx.x;
    const int vbase = blockIdx.x * VC_D;

    // stage: 16 rows x 512 = 2048 float4s... (16*512/4)=2048 f4 / 128 thr = 16 iters
#pragma unroll
    for (int k = 0; k < 16; ++k) {
        const int v = k;                  // all 128 threads cover one 2KB row
        const int c4 = tid;               // float4 column
        float4 x = *reinterpret_cast<const float4*>(
            Ct + ((size_t)(vbase + v) << 9) + (c4 << 2));
        unsigned short h0 = f2bf(x.x), h1 = f2bf(x.y), h2 = f2bf(x.z), h3 = f2bf(x.w);
        unsigned short l0 = f2bf(x.x - bf2f(h0)), l1 = f2bf(x.y - bf2f(h1)),
                       l2 = f2bf(x.z - bf2f(h2)), l3 = f2bf(x.w - bf2f(h3));
        int us = ((v << 9) + (c4 << 2)) ^ ((v & 7) << 3);   // XOR swizzle (16B units)
        *reinterpret_cast<ushort4*>(&Ch[us]) = make_ushort4(h0, h1, h2, h3);
        *reinterpret_cast<ushort4*>(&Cl[us]) = make_ushort4(l0, l1, l2, l3);
    }
    __syncthreads();

    const int wave = tid >> 6, lane = tid & 63;
    const int mt = wave;                        // 2 waves = 2 m-tiles (b 0-15 / 16-31)
    const int arow = mt * 16 + (lane & 15);     // b index for A-frag
    const int kblk = (lane >> 4) * 8;
    const int brow = lane & 15;                 // v-row in chunk for B-frag
    f32x4 acc = {0.f, 0.f, 0.f, 0.f};

    for (int kt = 0; kt < 16; ++kt) {
        const int koff = kt * 32 + kblk;
        // A-frag from u (fp32 -> bf16 hi/lo in-register)
        const float* up = u + (arow << 9) + koff;
        float4 a0 = *reinterpret_cast<const float4*>(up);
        float4 a1 = *reinterpret_cast<const float4*>(up + 4);
        float av[8] = {a0.x, a0.y, a0.z, a0.w, a1.x, a1.y, a1.z, a1.w};
        bf16x8 ah, al;
#pragma unroll
        for (int j = 0; j < 8; ++j) {
            unsigned short h = f2bf(av[j]);
            ah[j] = (short)h;
            al[j] = (short)f2bf(av[j] - bf2f(h));
        }
        const int rb = ((brow << 9) + koff) ^ ((brow & 7) << 3);
        bf16x8 bh = *reinterpret_cast<const bf16x8*>(&Ch[rb]);
        bf16x8 bl = *reinterpret_cast<const bf16x8*>(&Cl[rb]);
        acc = __builtin_amdgcn_mfma_f32_16x16x32_bf16(ah, bh, acc, 0, 0, 0);
        acc = __builtin_amdgcn_mfma_f32_16x16x32_bf16(ah, bl, acc, 0, 0, 0);
        acc = __builtin_amdgcn_mfma_f32_16x16x32_bf16(al, bh, acc, 0, 0, 0);
    }
    // C/D layout: col = lane&15 (n=v), row = (lane>>4)*4 + r (m=b)
    const int vcol = vbase + (lane & 15);
    const int b0 = mt * 16 + (lane >> 4) * 4;
#pragma unroll
    for (int r = 0; r < 4; ++r)
        D[(size_t)(b0 + r) * NV + vcol] = acc[r];
}

// ---------------------------------------------------------------------------
// scores + softmax + w-scatter: one block per b, thread = m.
//   s[m] = sum_l D[b][idx];  softmax over 128;  attn out;  w[b][.] scatter.
// ---------------------------------------------------------------------------
__global__ __launch_bounds__(128)
void scores_kernel(const float* __restrict__ D,
                   const int* __restrict__ inputs,
                   const int* __restrict__ lengths,
                   float* __restrict__ attn_out,   // [32][128] slice of d_out
                   float* __restrict__ w) {        // [32][NV]
    const int b = blockIdx.x, m = threadIdx.x;
    const float* Db = D + (size_t)b * NV;
    int idx[NL];
    const int4* ip = reinterpret_cast<const int4*>(inputs + (((b << 7) + m) << 5));
#pragma unroll
    for (int q = 0; q < 8; ++q) {
        int4 i4 = ip[q];
        idx[q * 4 + 0] = i4.x; idx[q * 4 + 1] = i4.y;
        idx[q * 4 + 2] = i4.z; idx[q * 4 + 3] = i4.w;
    }
    float s = 0.f;
#pragma unroll
    for (int l = 0; l < NL; ++l) s += Db[idx[l]];
    if (lengths[(b << 7) + m] == 0) s = NEG_INF;

    const int lane = m & 63, wv = m >> 6;
    __shared__ float red[2];
    float mx = s;
#pragma unroll
    for (int o = 32; o; o >>= 1) mx = fmaxf(mx, __shfl_xor(mx, o, 64));
    if (lane == 0) red[wv] = mx;
    __syncthreads();
    mx = fmaxf(red[0], red[1]);
    const float e = expf(s - mx);
    __syncthreads();
    float sum = e;
#pragma unroll
    for (int o = 32; o; o >>= 1) sum += __shfl_xor(sum, o, 64);
    if (lane == 0) red[wv] = sum;
    __syncthreads();
    const float a = e / (red[0] + red[1]);
    attn_out[(b << 7) + m] = a;

    float* wb = w + (size_t)b * NV;
    for (int i = m; i < NV; i += 128) wb[i] = 0.f;
    __syncthreads();
#pragma unroll
    for (int l = 0; l < NL; ++l) atomicAdd(&wb[idx[l]], a);
}

// ---------------------------------------------------------------------------
// gemm_U (split-K partial): part[blk][b][h] = sum_{v in chunk} w[b][v]*C[v][h]
// 256 thr, thread owns 2 h; w chunk broadcast from LDS; fp32 exact.
// ---------------------------------------------------------------------------
__global__ __launch_bounds__(256)
void gemm_U_kernel(const float* __restrict__ w,    // [32][NV]
                   const float* __restrict__ Ct,   // table h+1
                   float* __restrict__ part) {     // [NPART][32][512]
    __shared__ float wsm[NB][VC_U];
    const int tid = threadIdx.x;
    const int vbase = blockIdx.x * VC_U;
#pragma unroll
    for (int k = 0; k < 16; ++k) {
        int i = k * 256 + tid;           // 4096 = 32*128
        int b = i >> 7, v = i & 127;
        wsm[b][v] = w[(size_t)b * NV + vbase + v];
    }
    __syncthreads();
    const int h0 = tid << 1;
    float2 acc[NB];
#pragma unroll
    for (int b = 0; b < NB; ++b) acc[b] = make_float2(0.f, 0.f);

    for (int v = 0; v < VC_U; v += 2) {
        float2 c0 = *reinterpret_cast<const float2*>(Ct + ((size_t)(vbase + v) << 9) + h0);
        float2 c1 = *reinterpret_cast<const float2*>(Ct + ((size_t)(vbase + v + 1) << 9) + h0);
#pragma unroll
        for (int b = 0; b < NB; ++b) {
            float2 wv = *reinterpret_cast<const float2*>(&wsm[b][v]);
            acc[b].x += wv.x * c0.x + wv.y * c1.x;
            acc[b].y += wv.x * c0.y + wv.y * c1.y;
        }
    }
    float* pb = part + (size_t)blockIdx.x * NB * NH;
#pragma unroll
    for (int b = 0; b < NB; ++b)
        *reinterpret_cast<float2*>(pb + (b << 9) + h0) = acc[b];
}

// ---------------------------------------------------------------------------
// reduce partials + add previous u -> next u (or final output)
// ---------------------------------------------------------------------------
__global__ __launch_bounds__(256)
void reduce_u_kernel(const float* __restrict__ u_in,
                     const float* __restrict__ part,
                     float* __restrict__ u_out) {
    const int e = blockIdx.x * 256 + threadIdx.x;   // [0, 32*512)
    float a = u_in[e];
#pragma unroll 10
    for (int p = 0; p < NPART; ++p) a += part[(size_t)p * (NB * NH) + e];
    u_out[e] = a;
}

// ---------------------------------------------------------------------------
// Tiny-workspace fallback path (gather on the fly per hop).
// ---------------------------------------------------------------------------
__global__ __launch_bounds__(128)
void scores_gather_kernel(const int* __restrict__ inputs,
                          const float* __restrict__ Ctab,
                          const float* __restrict__ u_in,
                          const int* __restrict__ lengths,
                          float* __restrict__ scores) {
    const int bm = blockIdx.x;
    const int b = bm / NM;
    const int tid = threadIdx.x;
    __shared__ int idx[NL];
    if (tid < NL) idx[tid] = inputs[bm * NL + tid];
    __syncthreads();
    const int hoff = tid * 4;
    const float4 u4 = *reinterpret_cast<const float4*>(u_in + b * NH + hoff);
    float p = 0.f;
    for (int l = 0; l < NL; ++l) {
        const float4 v = *reinterpret_cast<const float4*>(
            Ctab + (size_t)idx[l] * NH + hoff);
        p += u4.x * v.x + u4.y * v.y + u4.z * v.z + u4.w * v.w;
    }
#pragma unroll
    for (int off = 32; off; off >>= 1) p += __shfl_down(p, off, 64);
    __shared__ float w2[2];
    if ((tid & 63) == 0) w2[tid >> 6] = p;
    __syncthreads();
    if (tid == 0) {
        float sres = w2[0] + w2[1];
        if (lengths[bm] == 0) sres = NEG_INF;
        scores[bm] = sres;
    }
}

__global__ __launch_bounds__(128)
void softmax_kernel(const float* __restrict__ scores,
                    float* __restrict__ attn_ws,
                    float* __restrict__ attn_out) {
    const int b = blockIdx.x;
    const int tid = threadIdx.x;
    const float s = scores[b * NM + tid];
    float p = s;
#pragma unroll
    for (int off = 32; off; off >>= 1) p = fmaxf(p, __shfl_down(p, off, 64));
    __shared__ float w2[2];
    if ((tid & 63) == 0) w2[tid >> 6] = p;
    __syncthreads();
    const float mx = fmaxf(w2[0], w2[1]);
    const float e = expf(s - mx);
    float q = e;
#pragma unroll
    for (int off = 32; off; off >>= 1) q += __shfl_down(q, off, 64);
    __shared__ float w3[2];
    if ((tid & 63) == 0) w3[tid >> 6] = q;
    __syncthreads();
    const float a = e / (w3[0] + w3[1]);
    attn_ws[b * NM + tid] = a;
    attn_out[b * NM + tid] = a;
}

__global__ __launch_bounds__(512)
void update_gather_kernel(const int* __restrict__ inputs,
                          const float* __restrict__ Ctab,
                          const float* __restrict__ u_in,
                          const float* __restrict__ attn,
                          float* __restrict__ u_out) {
    const int b = blockIdx.x;
    const int tid = threadIdx.x;
    __shared__ float a_s[NM];
    __shared__ int idx_s[NM * NL];
    if (tid < NM) a_s[tid] = attn[b * NM + tid];
    for (int i = tid; i < NM * NL; i += 512) idx_s[i] = inputs[b * NM * NL + i];
    __syncthreads();
    float acc = u_in[b * NH + tid];
    for (int m = 0; m < NM; ++m) {
        const float a = a_s[m];
        float part = 0.f;
        for (int l = 0; l < NL; ++l) {
            part += Ctab[(size_t)idx_s[m * NL + l] * NH + tid];
        }
        acc += a * part;
    }
    u_out[b * NH + tid] = acc;
}

// ---------------------------------------------------------------------------
extern "C" void kernel_launch(void* const* d_in, const int* in_sizes, int n_in,
                              void* d_out, int out_size, void* d_ws, size_t ws_size,
                              hipStream_t stream) {
    const int*   inputs  = (const int*)d_in[0];
    const int*   lengths = (const int*)d_in[1];
    const float* enc     = (const float*)d_in[2];
    const float* C       = (const float*)d_in[3];

    float* out     = (float*)d_out;
    float* u_final = out;                  // [32][512]
    float* attns   = out + NB * NH;        // [3][32][128]

    const size_t TAB = (size_t)NV * NH;
    const size_t BV  = (size_t)NB * NV;    // 1,024,000
    const size_t U_ELEMS = (size_t)NB * NH;
    float* ws = (float*)d_ws;

    const size_t need = (2 * BV + 2 * U_ELEMS + (size_t)NPART * U_ELEMS) * sizeof(float);

    if (ws_size >= need) {
        float* D    = ws;
        float* w    = D + BV;
        float* u1   = w + BV;
        float* u2   = u1 + U_ELEMS;
        float* part = u2 + U_ELEMS;

        const float* uin[NHOPS]  = {enc, u1, u2};
        float*       unext[NHOPS] = {u1, u2, u_final};
        for (int h = 0; h < NHOPS; ++h) {
            gemm_D_kernel<<<NV / VC_D, 128, 0, stream>>>(uin[h], C + (size_t)h * TAB, D);
            scores_kernel<<<NB, 128, 0, stream>>>(D, inputs, lengths,
                                                  attns + (size_t)h * NB * NM, w);
            gemm_U_kernel<<<NPART, 256, 0, stream>>>(w, C + (size_t)(h + 1) * TAB, part);
            reduce_u_kernel<<<(NB * NH) / 256, 256, 0, stream>>>(uin[h], part, unext[h]);
        }
    } else {
        // Tiny-workspace fallback: gather on the fly per hop.
        float* scores  = ws;
        float* attn_ws = ws + NB * NM;
        float* u1      = attn_ws + NB * NM;
        float* u2      = u1 + U_ELEMS;
        const float* uin = enc;
        float* uou[NHOPS] = {u1, u2, u_final};
        for (int h = 0; h < NHOPS; ++h) {
            scores_gather_kernel<<<NB * NM, 128, 0, stream>>>(
                inputs, C + (size_t)h * TAB, uin, lengths, scores);
            softmax_kernel<<<NB, 128, 0, stream>>>(
                scores, attn_ws, attns + (size_t)h * NB * NM);
            update_gather_kernel<<<NB, 512, 0, stream>>>(
                inputs, C + (size_t)(h + 1) * TAB, uin, attn_ws, uou[h]);
            uin = uou[h];
        }
    }
}

// Round 4
// 294.802 us; speedup vs baseline: 1.4138x; 1.4138x over previous
//
#include <hip/hip_runtime.h>

#define NB 32
#define NM 128
#define NL 32
#define NH 512
#define NV 32000
#define NHOPS 3
#define NEG_INF -1e9f

#define VC_D 16
#define ND_BLK (NV / VC_D)      // 2000 blocks for gemm_D
#define VC_U 64
#define NPART (NV / VC_U)       // 500 split-K partials

typedef __attribute__((ext_vector_type(8))) short bf16x8;
typedef __attribute__((ext_vector_type(4))) float f32x4;

__device__ __forceinline__ unsigned short f2bf(float x) {
    unsigned u = __float_as_uint(x);
    return (unsigned short)((u + 0x7fffu + ((u >> 16) & 1u)) >> 16);
}
__device__ __forceinline__ float bf2f(unsigned short h) {
    return __uint_as_float(((unsigned)h) << 16);
}

// ---------------------------------------------------------------------------
// u (fp32 [32][512]) -> bf16 hi/lo split, once per hop (hop0 standalone).
// ---------------------------------------------------------------------------
__global__ __launch_bounds__(256)
void ubf_kernel(const float* __restrict__ u,
                unsigned short* __restrict__ uh,
                unsigned short* __restrict__ ul) {
    const int e = blockIdx.x * 256 + threadIdx.x;   // grid 64
    const float x = u[e];
    const unsigned short h = f2bf(x);
    uh[e] = h;
    ul[e] = f2bf(x - bf2f(h));
}

// ---------------------------------------------------------------------------
// gemm_D: D[b][v] = u[b] . C[v]   (M=32, N=v, K=512), split-bf16 (3 MFMA).
// A-frags (u) pre-converted; table staged to LDS as bf16 hi/lo, XOR-swizzled.
// ---------------------------------------------------------------------------
__global__ __launch_bounds__(128)
void gemm_D_kernel(const unsigned short* __restrict__ uh,
                   const unsigned short* __restrict__ ul,
                   const float* __restrict__ Ct,
                   float* __restrict__ D) {
    __shared__ __align__(16) unsigned short Ch[VC_D * NH];
    __shared__ __align__(16) unsigned short Cl[VC_D * NH];
    const int tid = threadIdx.x;
    const int vbase = blockIdx.x * VC_D;

#pragma unroll
    for (int k = 0; k < VC_D; ++k) {
        const float4 x = *reinterpret_cast<const float4*>(
            Ct + ((size_t)(vbase + k) << 9) + (tid << 2));
        const unsigned short h0 = f2bf(x.x), h1 = f2bf(x.y),
                             h2 = f2bf(x.z), h3 = f2bf(x.w);
        const unsigned short l0 = f2bf(x.x - bf2f(h0)), l1 = f2bf(x.y - bf2f(h1)),
                             l2 = f2bf(x.z - bf2f(h2)), l3 = f2bf(x.w - bf2f(h3));
        const int us = ((k << 9) + (tid << 2)) ^ ((k & 7) << 3);
        *reinterpret_cast<ushort4*>(&Ch[us]) = make_ushort4(h0, h1, h2, h3);
        *reinterpret_cast<ushort4*>(&Cl[us]) = make_ushort4(l0, l1, l2, l3);
    }
    __syncthreads();

    const int wave = tid >> 6, lane = tid & 63;
    const int arow = wave * 16 + (lane & 15);   // b row
    const int kblk = (lane >> 4) * 8;
    const int brow = lane & 15;                 // v row in chunk
    f32x4 acc = {0.f, 0.f, 0.f, 0.f};

    for (int kt = 0; kt < 16; ++kt) {
        const int koff = kt * 32 + kblk;
        const bf16x8 ah = *reinterpret_cast<const bf16x8*>(uh + (arow << 9) + koff);
        const bf16x8 al = *reinterpret_cast<const bf16x8*>(ul + (arow << 9) + koff);
        const int rb = ((brow << 9) + koff) ^ ((brow & 7) << 3);
        const bf16x8 bh = *reinterpret_cast<const bf16x8*>(&Ch[rb]);
        const bf16x8 bl = *reinterpret_cast<const bf16x8*>(&Cl[rb]);
        acc = __builtin_amdgcn_mfma_f32_16x16x32_bf16(ah, bh, acc, 0, 0, 0);
        acc = __builtin_amdgcn_mfma_f32_16x16x32_bf16(ah, bl, acc, 0, 0, 0);
        acc = __builtin_amdgcn_mfma_f32_16x16x32_bf16(al, bh, acc, 0, 0, 0);
    }
    const int vcol = vbase + (lane & 15);
    const int b0 = wave * 16 + (lane >> 4) * 4;
#pragma unroll
    for (int r = 0; r < 4; ++r)
        D[(size_t)(b0 + r) * NV + vcol] = acc[r];
}

// ---------------------------------------------------------------------------
// scores + softmax + w scatter: one block per b (256 thr; tid<128 = m).
// ---------------------------------------------------------------------------
__global__ __launch_bounds__(256)
void scores_kernel(const float* __restrict__ D,
                   const int* __restrict__ inputs,
                   const int* __restrict__ lengths,
                   float* __restrict__ attn_out,   // [32][128]
                   float* __restrict__ w) {        // [32][NV]
    const int b = blockIdx.x, tid = threadIdx.x;
    float* wb = w + (size_t)b * NV;

    // zero this block's w row (coalesced float4)
    float4* wb4 = reinterpret_cast<float4*>(wb);
    for (int i = tid; i < NV / 4; i += 256)
        wb4[i] = make_float4(0.f, 0.f, 0.f, 0.f);

    int idx[NL];
    float s = NEG_INF;
    if (tid < NM) {
        const int4* ip = reinterpret_cast<const int4*>(
            inputs + (((b << 7) + tid) << 5));
        const float* Db = D + (size_t)b * NV;
        float acc = 0.f;
#pragma unroll
        for (int q = 0; q < 8; ++q) {
            const int4 i4 = ip[q];
            idx[q * 4 + 0] = i4.x; idx[q * 4 + 1] = i4.y;
            idx[q * 4 + 2] = i4.z; idx[q * 4 + 3] = i4.w;
        }
#pragma unroll
        for (int l = 0; l < NL; ++l) acc += Db[idx[l]];
        s = (lengths[(b << 7) + tid] == 0) ? NEG_INF : acc;
    }

    __shared__ float red[2];
    float mx = s;
#pragma unroll
    for (int o = 32; o; o >>= 1) mx = fmaxf(mx, __shfl_xor(mx, o, 64));
    if (tid < NM && (tid & 63) == 0) red[tid >> 6] = mx;
    __syncthreads();
    mx = fmaxf(red[0], red[1]);
    const float ee = (tid < NM) ? expf(s - mx) : 0.f;
    float sum = ee;
#pragma unroll
    for (int o = 32; o; o >>= 1) sum += __shfl_xor(sum, o, 64);
    __syncthreads();
    if (tid < NM && (tid & 63) == 0) red[tid >> 6] = sum;
    __syncthreads();
    if (tid < NM) {
        const float a = ee / (red[0] + red[1]);
        attn_out[(b << 7) + tid] = a;
#pragma unroll
        for (int l = 0; l < NL; ++l) atomicAdd(&wb[idx[l]], a);
    }
}

// ---------------------------------------------------------------------------
// gemm_U (split-K): part[blk][b][h] = sum_{v in 64-chunk} w[b][v]*C[v][h]
// 500 blocks (2/CU), 256 thr; v-loop unrolled x4 with batched row loads.
// ---------------------------------------------------------------------------
__global__ __launch_bounds__(256)
void gemm_U_kernel(const float* __restrict__ w,
                   const float* __restrict__ Ct,
                   float* __restrict__ part) {     // [NPART][32][512]
    __shared__ float wsm[NB][VC_U];                // 8 KB
    const int tid = threadIdx.x;
    const int vbase = blockIdx.x * VC_U;
#pragma unroll
    for (int k = 0; k < (NB * VC_U) / 256; ++k) {  // 8 iters
        const int i = k * 256 + tid;
        const int b = i >> 6, v = i & 63;
        wsm[b][v] = w[(size_t)b * NV + vbase + v];
    }
    __syncthreads();

    const int h0 = tid << 1;
    float2 acc[NB];
#pragma unroll
    for (int b = 0; b < NB; ++b) acc[b] = make_float2(0.f, 0.f);

    for (int v = 0; v < VC_U; v += 4) {
        const float2 c0 = *reinterpret_cast<const float2*>(Ct + ((size_t)(vbase + v + 0) << 9) + h0);
        const float2 c1 = *reinterpret_cast<const float2*>(Ct + ((size_t)(vbase + v + 1) << 9) + h0);
        const float2 c2 = *reinterpret_cast<const float2*>(Ct + ((size_t)(vbase + v + 2) << 9) + h0);
        const float2 c3 = *reinterpret_cast<const float2*>(Ct + ((size_t)(vbase + v + 3) << 9) + h0);
#pragma unroll
        for (int b = 0; b < NB; ++b) {
            const float4 wv = *reinterpret_cast<const float4*>(&wsm[b][v]);
            acc[b].x += wv.x * c0.x + wv.y * c1.x + wv.z * c2.x + wv.w * c3.x;
            acc[b].y += wv.x * c0.y + wv.y * c1.y + wv.z * c2.y + wv.w * c3.y;
        }
    }
    float* pb = part + (size_t)blockIdx.x * NB * NH;
#pragma unroll
    for (int b = 0; b < NB; ++b)
        *reinterpret_cast<float2*>(pb + (b << 9) + h0) = acc[b];
}

// ---------------------------------------------------------------------------
// reduce partials (4-way split over q) + add u_in -> u_next; fuse bf16 split.
// grid 256 blocks x 256 thr; block covers 64 elements.
// ---------------------------------------------------------------------------
__global__ __launch_bounds__(256)
void reduce_u_kernel(const float* __restrict__ u_in,
                     const float* __restrict__ part,
                     float* __restrict__ u_out,
                     unsigned short* __restrict__ uh,
                     unsigned short* __restrict__ ul) {
    const int j = threadIdx.x & 63, q = threadIdx.x >> 6;
    const int e = blockIdx.x * 64 + j;
    float s = 0.f;
    const int p0 = q * (NPART / 4), p1 = p0 + (NPART / 4);
#pragma unroll 5
    for (int p = p0; p < p1; ++p) s += part[(size_t)p * (NB * NH) + e];
    __shared__ float red[4][64];
    red[q][j] = s;
    __syncthreads();
    if (threadIdx.x < 64) {
        const float t = u_in[e] + red[0][j] + red[1][j] + red[2][j] + red[3][j];
        u_out[e] = t;
        const unsigned short h = f2bf(t);
        uh[e] = h;
        ul[e] = f2bf(t - bf2f(h));
    }
}

// ---------------------------------------------------------------------------
// Tiny-workspace fallback path (gather on the fly per hop).
// ---------------------------------------------------------------------------
__global__ __launch_bounds__(128)
void scores_gather_kernel(const int* __restrict__ inputs,
                          const float* __restrict__ Ctab,
                          const float* __restrict__ u_in,
                          const int* __restrict__ lengths,
                          float* __restrict__ scores) {
    const int bm = blockIdx.x;
    const int b = bm / NM;
    const int tid = threadIdx.x;
    __shared__ int idx[NL];
    if (tid < NL) idx[tid] = inputs[bm * NL + tid];
    __syncthreads();
    const int hoff = tid * 4;
    const float4 u4 = *reinterpret_cast<const float4*>(u_in + b * NH + hoff);
    float p = 0.f;
    for (int l = 0; l < NL; ++l) {
        const float4 v = *reinterpret_cast<const float4*>(
            Ctab + (size_t)idx[l] * NH + hoff);
        p += u4.x * v.x + u4.y * v.y + u4.z * v.z + u4.w * v.w;
    }
#pragma unroll
    for (int off = 32; off; off >>= 1) p += __shfl_down(p, off, 64);
    __shared__ float w2[2];
    if ((tid & 63) == 0) w2[tid >> 6] = p;
    __syncthreads();
    if (tid == 0) {
        float sres = w2[0] + w2[1];
        if (lengths[bm] == 0) sres = NEG_INF;
        scores[bm] = sres;
    }
}

__global__ __launch_bounds__(128)
void softmax_kernel(const float* __restrict__ scores,
                    float* __restrict__ attn_ws,
                    float* __restrict__ attn_out) {
    const int b = blockIdx.x;
    const int tid = threadIdx.x;
    const float s = scores[b * NM + tid];
    float p = s;
#pragma unroll
    for (int off = 32; off; off >>= 1) p = fmaxf(p, __shfl_down(p, off, 64));
    __shared__ float w2[2];
    if ((tid & 63) == 0) w2[tid >> 6] = p;
    __syncthreads();
    const float mx = fmaxf(w2[0], w2[1]);
    const float e = expf(s - mx);
    float q = e;
#pragma unroll
    for (int off = 32; off; off >>= 1) q += __shfl_down(q, off, 64);
    __shared__ float w3[2];
    if ((tid & 63) == 0) w3[tid >> 6] = q;
    __syncthreads();
    const float a = e / (w3[0] + w3[1]);
    attn_ws[b * NM + tid] = a;
    attn_out[b * NM + tid] = a;
}

__global__ __launch_bounds__(512)
void update_gather_kernel(const int* __restrict__ inputs,
                          const float* __restrict__ Ctab,
                          const float* __restrict__ u_in,
                          const float* __restrict__ attn,
                          float* __restrict__ u_out) {
    const int b = blockIdx.x;
    const int tid = threadIdx.x;
    __shared__ float a_s[NM];
    __shared__ int idx_s[NM * NL];
    if (tid < NM) a_s[tid] = attn[b * NM + tid];
    for (int i = tid; i < NM * NL; i += 512) idx_s[i] = inputs[b * NM * NL + i];
    __syncthreads();
    float acc = u_in[b * NH + tid];
    for (int m = 0; m < NM; ++m) {
        const float a = a_s[m];
        float part = 0.f;
        for (int l = 0; l < NL; ++l) {
            part += Ctab[(size_t)idx_s[m * NL + l] * NH + tid];
        }
        acc += a * part;
    }
    u_out[b * NH + tid] = acc;
}

// ---------------------------------------------------------------------------
extern "C" void kernel_launch(void* const* d_in, const int* in_sizes, int n_in,
                              void* d_out, int out_size, void* d_ws, size_t ws_size,
                              hipStream_t stream) {
    const int*   inputs  = (const int*)d_in[0];
    const int*   lengths = (const int*)d_in[1];
    const float* enc     = (const float*)d_in[2];
    const float* C       = (const float*)d_in[3];

    float* out     = (float*)d_out;
    float* u_final = out;                  // [32][512]
    float* attns   = out + NB * NH;        // [3][32][128]

    const size_t TAB = (size_t)NV * NH;
    const size_t BV  = (size_t)NB * NV;    // 1,024,000
    const size_t UE  = (size_t)NB * NH;    // 16,384
    float* ws = (float*)d_ws;

    const size_t need_f = 2 * BV + (size_t)NPART * UE + 2 * UE + UE; // +UE for uh/ul region
    if (ws_size >= need_f * sizeof(float)) {
        float* D    = ws;
        float* w    = D + BV;
        float* part = w + BV;
        float* u1   = part + (size_t)NPART * UE;
        float* u2   = u1 + UE;
        unsigned short* uh = (unsigned short*)(u2 + UE);
        unsigned short* ul = uh + UE;

        ubf_kernel<<<UE / 256, 256, 0, stream>>>(enc, uh, ul);
        const float* uin[NHOPS]   = {enc, u1, u2};
        float*       unext[NHOPS] = {u1, u2, u_final};
        for (int h = 0; h < NHOPS; ++h) {
            gemm_D_kernel<<<ND_BLK, 128, 0, stream>>>(uh, ul, C + (size_t)h * TAB, D);
            scores_kernel<<<NB, 256, 0, stream>>>(D, inputs, lengths,
                                                  attns + (size_t)h * NB * NM, w);
            gemm_U_kernel<<<NPART, 256, 0, stream>>>(w, C + (size_t)(h + 1) * TAB, part);
            reduce_u_kernel<<<UE / 64, 256, 0, stream>>>(uin[h], part, unext[h], uh, ul);
        }
    } else {
        // Tiny-workspace fallback: gather on the fly per hop.
        float* scores  = ws;
        float* attn_ws = ws + NB * NM;
        float* u1      = attn_ws + NB * NM;
        float* u2      = u1 + UE;
        const float* uin = enc;
        float* uou[NHOPS] = {u1, u2, u_final};
        for (int h = 0; h < NHOPS; ++h) {
            scores_gather_kernel<<<NB * NM, 128, 0, stream>>>(
                inputs, C + (size_t)h * TAB, uin, lengths, scores);
            softmax_kernel<<<NB, 128, 0, stream>>>(
                scores, attn_ws, attns + (size_t)h * NB * NM);
            update_gather_kernel<<<NB, 512, 0, stream>>>(
                inputs, C + (size_t)(h + 1) * TAB, uin, attn_ws, uou[h]);
            uin = uou[h];
        }
    }
}